// Round 1
// baseline (644.295 us; speedup 1.0000x reference)
//
#include <hip/hip_runtime.h>
#include <math.h>

#define PI_F 3.14159265358979323846f
#define IMG 65536  // 256*256

__device__ __forceinline__ float2 cmul(float2 a, float2 b) {
  return make_float2(a.x * b.x - a.y * b.y, a.x * b.y + a.y * b.x);
}

// 128-entry twiddle table: tw[j] = (cos(pi*j/128), sin(pi*j/128))
__device__ __forceinline__ void build_tw(float2* tw) {
  if (threadIdx.x < 128) {
    float sn, cs;
    sincosf(PI_F * (float)threadIdx.x * (1.f / 128.f), &sn, &cs);
    tw[threadIdx.x] = make_float2(cs, sn);
  }
}

// Stockham radix-2 FFT of 256 points, one wave (64 lanes) per row.
// Input in sb[0][wave][0..255]; result in sb[0][wave][0..255].
// sign = -1 forward, +1 inverse (unnormalized).
__device__ __forceinline__ void fft256(float2 (*sb)[4][256], const float2* tw,
                                       int wave, int lane, float sign) {
  #pragma unroll
  for (int pp = 0; pp < 8; ++pp) {
    __syncthreads();
    const int p = 1 << pp;
    const float2* src = sb[pp & 1][wave];
    float2* dst = sb[(pp & 1) ^ 1][wave];
    #pragma unroll
    for (int r = 0; r < 2; ++r) {
      int i = lane + (r << 6);
      int k = i & (p - 1);
      float2 u0 = src[i];
      float2 u1 = src[i + 128];
      float2 w = tw[k << (7 - pp)];
      float cs = w.x, sn = sign * w.y;
      float2 t = make_float2(u1.x * cs - u1.y * sn, u1.x * sn + u1.y * cs);
      int j = ((i - k) << 1) + k;
      dst[j]     = make_float2(u0.x + t.x, u0.y + t.y);
      dst[j + p] = make_float2(u0.x - t.x, u0.y - t.y);
    }
  }
  __syncthreads();
}

// ---------------- filter construction ----------------

// Per-filter sums gs, ws (for Morlet DC correction). grid = (8), block = 256.
__global__ __launch_bounds__(256) void k_sums(const float* th, const float* xi,
                                              const float* sg, const float* sl,
                                              float* sums) {
  int f = blockIdx.x, t = threadIdx.x;
  float c, s;
  sincosf(th[f], &s, &c);
  float X = xi[f], S = sg[f], SL = sl[f];
  float a0x = SL * c / S, a0y = SL * s / S, a1x = -s / S, a1y = c / S;
  float gs = 0.f, wr = 0.f, wi = 0.f;
  for (int p = t; p < IMG; p += 256) {
    float gm = (float)((p >> 8) - 128);
    float gn = (float)((p & 255) - 128);
    float r0 = a0x * gm + a0y * gn, r1 = a1x * gm + a1y * gn;
    float g = __expf(-0.5f * (r0 * r0 + r1 * r1));
    float sp, cp;
    sincosf(X * (c * gm + s * gn), &sp, &cp);
    gs += g; wr += cp * g; wi += sp * g;
  }
  __shared__ float red[3][256];
  red[0][t] = gs; red[1][t] = wr; red[2][t] = wi;
  __syncthreads();
  for (int o = 128; o > 0; o >>= 1) {
    if (t < o) {
      red[0][t] += red[0][t + o];
      red[1][t] += red[1][t + o];
      red[2][t] += red[2][t + o];
    }
    __syncthreads();
  }
  if (t == 0) {
    sums[f * 3 + 0] = red[0][0];
    sums[f * 3 + 1] = red[1][0];
    sums[f * 3 + 2] = red[2][0];
  }
}

// Spatial filters with ifftshift folded in. f=0..7 psi (Morlet), f=8 phi.
// grid = (256, 9), block = 256; one thread per pixel.
__global__ __launch_bounds__(256) void k_spatial(const float* th, const float* xi,
                                                 const float* sg, const float* sl,
                                                 const float* sums, float2* spat) {
  int f = blockIdx.y;
  int p = blockIdx.x * 256 + threadIdx.x;
  int m = p >> 8, n = p & 255;
  // ifftshift fold: stored position (m,n) evaluates grid coord (m<128?m:m-256)
  float gm = (m < 128) ? (float)m : (float)(m - 256);
  float gn = (n < 128) ? (float)n : (float)(n - 256);
  bool isPhi = (f == 8);
  float T = isPhi ? 0.f : th[f];
  float X = isPhi ? 0.f : xi[f];
  float S = isPhi ? 3.2f : sg[f];   // phi: sigma = 0.8 * 2^J, J=2
  float SL = isPhi ? 1.f : sl[f];
  float c, s;
  sincosf(T, &s, &c);
  float a0x = SL * c / S, a0y = SL * s / S, a1x = -s / S, a1y = c / S;
  float r0 = a0x * gm + a0y * gn, r1 = a1x * gm + a1y * gn;
  float g = __expf(-0.5f * (r0 * r0 + r1 * r1));
  float sp, cp;
  sincosf(X * (c * gm + s * gn), &sp, &cp);
  float re, im;
  if (!isPhi) {
    float gs = sums[f * 3];
    float Kr = sums[f * 3 + 1] / gs, Ki = sums[f * 3 + 2] / gs;
    re = (cp - Kr) * g;
    im = (sp - Ki) * g;
  } else {
    re = g;
    im = 0.f;
  }
  float inorm = SL / (2.f * PI_F * S * S);
  spat[(size_t)f * IMG + p] = make_float2(re * inorm, im * inorm);
}

// ---------------- generic FFT pass kernels ----------------
// All: block = 256 (4 waves), each wave handles row = blockIdx.x*4 + wave.
// grid = (64, n_images).

// complex in -> FFT along contiguous axis -> TRANSPOSED out
__global__ __launch_bounds__(256) void k_passT(const float2* __restrict__ in,
                                               float2* __restrict__ out, float sign) {
  __shared__ float2 sb[2][4][256];
  __shared__ float2 tw[128];
  build_tw(tw);
  int wave = threadIdx.x >> 6, lane = threadIdx.x & 63;
  int img = blockIdx.y, row = blockIdx.x * 4 + wave;
  const float2* ip = in + (size_t)img * IMG + (size_t)row * 256;
  #pragma unroll
  for (int r = 0; r < 4; r++) sb[0][wave][lane + 64 * r] = ip[lane + 64 * r];
  fft256(sb, tw, wave, lane, sign);
  float2* op = out + (size_t)img * IMG + row;
  #pragma unroll
  for (int r = 0; r < 4; r++) {
    int j = lane + 64 * r;
    op[(size_t)j * 256] = sb[0][wave][j];
  }
}

// real in -> FFT -> TRANSPOSED out
__global__ __launch_bounds__(256) void k_passT_real(const float* __restrict__ in,
                                                    float2* __restrict__ out, float sign) {
  __shared__ float2 sb[2][4][256];
  __shared__ float2 tw[128];
  build_tw(tw);
  int wave = threadIdx.x >> 6, lane = threadIdx.x & 63;
  int img = blockIdx.y, row = blockIdx.x * 4 + wave;
  const float* ip = in + (size_t)img * IMG + (size_t)row * 256;
  #pragma unroll
  for (int r = 0; r < 4; r++)
    sb[0][wave][lane + 64 * r] = make_float2(ip[lane + 64 * r], 0.f);
  fft256(sb, tw, wave, lane, sign);
  float2* op = out + (size_t)img * IMG + row;
  #pragma unroll
  for (int r = 0; r < 4; r++) {
    int j = lane + 64 * r;
    op[(size_t)j * 256] = sb[0][wave][j];
  }
}

// complex in -> FFT -> STRAIGHT out (supports in == out; no __restrict__)
__global__ __launch_bounds__(256) void k_passS(const float2* in, float2* out, float sign) {
  __shared__ float2 sb[2][4][256];
  __shared__ float2 tw[128];
  build_tw(tw);
  int wave = threadIdx.x >> 6, lane = threadIdx.x & 63;
  int img = blockIdx.y, row = blockIdx.x * 4 + wave;
  const float2* ip = in + (size_t)img * IMG + (size_t)row * 256;
  #pragma unroll
  for (int r = 0; r < 4; r++) sb[0][wave][lane + 64 * r] = ip[lane + 64 * r];
  fft256(sb, tw, wave, lane, sign);
  float2* op = out + (size_t)img * IMG + (size_t)row * 256;
  #pragma unroll
  for (int r = 0; r < 4; r++) {
    int j = lane + 64 * r;
    op[j] = sb[0][wave][j];
  }
}

// shared body: load A*P row, inverse FFT, transposed store
__device__ __forceinline__ void mul_ifft_storeT(const float2* a, const float2* p,
                                                float2* oT, float2 (*sb)[4][256],
                                                const float2* tw, int wave, int lane) {
  #pragma unroll
  for (int r = 0; r < 4; r++) {
    int j = lane + 64 * r;
    sb[0][wave][j] = cmul(a[j], p[j]);
  }
  fft256(sb, tw, wave, lane, 1.f);
  #pragma unroll
  for (int r = 0; r < 4; r++) {
    int j = lane + 64 * r;
    oT[(size_t)j * 256] = sb[0][wave][j];
  }
}

// S0 pass1: XhT[y] * phiT -> ifft(m) -> transposed -> s0t[y].  grid (64, 8)
__global__ __launch_bounds__(256) void k_s0_p1(const float2* __restrict__ XhT,
                                               const float2* __restrict__ phiT,
                                               float2* __restrict__ s0t) {
  __shared__ float2 sb[2][4][256];
  __shared__ float2 tw[128];
  build_tw(tw);
  int wave = threadIdx.x >> 6, lane = threadIdx.x & 63;
  int img = blockIdx.y, row = blockIdx.x * 4 + wave;
  mul_ifft_storeT(XhT + (size_t)img * IMG + (size_t)row * 256,
                  phiT + (size_t)row * 256,
                  s0t + (size_t)img * IMG + row, sb, tw, wave, lane);
}

// S0 pass2: s0t row -> ifft(n) -> real/65536 -> out channel k=0.  grid (64, 8)
__global__ __launch_bounds__(256) void k_s0_p2(const float2* __restrict__ s0t,
                                               float* __restrict__ out) {
  __shared__ float2 sb[2][4][256];
  __shared__ float2 tw[128];
  build_tw(tw);
  int wave = threadIdx.x >> 6, lane = threadIdx.x & 63;
  int img = blockIdx.y, row = blockIdx.x * 4 + wave;  // row = m
  const float2* ip = s0t + (size_t)img * IMG + (size_t)row * 256;
  #pragma unroll
  for (int r = 0; r < 4; r++) sb[0][wave][lane + 64 * r] = ip[lane + 64 * r];
  fft256(sb, tw, wave, lane, 1.f);
  float* op = out + ((size_t)img * 73) * IMG + (size_t)row * 256;
  #pragma unroll
  for (int r = 0; r < 4; r++) {
    int j = lane + 64 * r;
    op[j] = sb[0][wave][j].x * (1.f / 65536.f);
  }
}

// U1 pass1: XhT[i]*psiT[f] -> ifft(m) -> transposed -> T1 (parked in d_out U2 slots)
// grid (64, 64); y = i*8+f
__global__ __launch_bounds__(256) void k_u1_p1(const float2* __restrict__ XhT,
                                               const float2* __restrict__ psiT,
                                               float* out) {
  __shared__ float2 sb[2][4][256];
  __shared__ float2 tw[128];
  build_tw(tw);
  int wave = threadIdx.x >> 6, lane = threadIdx.x & 63;
  int u = blockIdx.y, i = u >> 3, f = u & 7;
  int row = blockIdx.x * 4 + wave;  // row = n
  float2* t1 = (float2*)out + ((size_t)(i * 73 + 9 + 2 * f)) * 32768 + row;
  mul_ifft_storeT(XhT + (size_t)i * IMG + (size_t)row * 256,
                  psiT + (size_t)f * IMG + (size_t)row * 256,
                  t1, sb, tw, wave, lane);
}

// U1 pass2: T1 row m -> ifft(n) -> |z|/65536 -> out U1; then fwd fft(n) -> transposed -> T2
// grid (64, 64)
__global__ __launch_bounds__(256) void k_u1_p2(float* out, float2* T2) {
  __shared__ float2 sb[2][4][256];
  __shared__ float2 tw[128];
  build_tw(tw);
  int wave = threadIdx.x >> 6, lane = threadIdx.x & 63;
  int u = blockIdx.y, i = u >> 3, f = u & 7;
  int row = blockIdx.x * 4 + wave;  // row = m
  const float2* t1 = (const float2*)out + ((size_t)(i * 73 + 9 + 2 * f)) * 32768
                     + (size_t)row * 256;
  #pragma unroll
  for (int r = 0; r < 4; r++) sb[0][wave][lane + 64 * r] = t1[lane + 64 * r];
  fft256(sb, tw, wave, lane, 1.f);  // inverse along n -> spatial row m
  float* uo = out + ((size_t)(i * 73 + 1 + f)) * IMG + (size_t)row * 256;
  #pragma unroll
  for (int r = 0; r < 4; r++) {
    int j = lane + 64 * r;
    float2 z = sb[0][wave][j];
    float mod = sqrtf(z.x * z.x + z.y * z.y) * (1.f / 65536.f);
    uo[j] = mod;                        // coalesced U1 output
    sb[0][wave][j] = make_float2(mod, 0.f);
  }
  fft256(sb, tw, wave, lane, -1.f);  // forward along n
  float2* t2 = T2 + (size_t)u * IMG + row;
  #pragma unroll
  for (int r = 0; r < 4; r++) {
    int j = lane + 64 * r;
    t2[(size_t)j * 256] = sb[0][wave][j];
  }
}

// U2 pass1 (chunked): U1hT[(i0+i')*8+f1] * psiT[f2] -> ifft(m) -> transposed -> T3
// grid (64, nI*8); y -> i' = y>>3, f2 = y&7
__global__ __launch_bounds__(256) void k_u2_p1(const float2* __restrict__ U1hT,
                                               const float2* __restrict__ psiT,
                                               float2* __restrict__ T3,
                                               int f1, int i0) {
  __shared__ float2 sb[2][4][256];
  __shared__ float2 tw[128];
  build_tw(tw);
  int wave = threadIdx.x >> 6, lane = threadIdx.x & 63;
  int y = blockIdx.y, ii = i0 + (y >> 3), f2 = y & 7;
  int row = blockIdx.x * 4 + wave;  // row = n
  mul_ifft_storeT(U1hT + ((size_t)(ii * 8 + f1)) * IMG + (size_t)row * 256,
                  psiT + (size_t)f2 * IMG + (size_t)row * 256,
                  T3 + (size_t)y * IMG + row, sb, tw, wave, lane);
}

// U2 pass2: T3 row m -> ifft(n) -> |z|/65536 -> out U2.  grid (64, nI*8)
__global__ __launch_bounds__(256) void k_u2_p2(const float2* __restrict__ T3,
                                               float* __restrict__ out,
                                               int f1, int i0) {
  __shared__ float2 sb[2][4][256];
  __shared__ float2 tw[128];
  build_tw(tw);
  int wave = threadIdx.x >> 6, lane = threadIdx.x & 63;
  int y = blockIdx.y, ii = i0 + (y >> 3), f2 = y & 7;
  int row = blockIdx.x * 4 + wave;  // row = m
  const float2* ip = T3 + (size_t)y * IMG + (size_t)row * 256;
  #pragma unroll
  for (int r = 0; r < 4; r++) sb[0][wave][lane + 64 * r] = ip[lane + 64 * r];
  fft256(sb, tw, wave, lane, 1.f);
  float* op = out + ((size_t)(ii * 73 + 9 + f1 * 8 + f2)) * IMG + (size_t)row * 256;
  #pragma unroll
  for (int r = 0; r < 4; r++) {
    int j = lane + 64 * r;
    float2 z = sb[0][wave][j];
    op[j] = sqrtf(z.x * z.x + z.y * z.y) * (1.f / 65536.f);
  }
}

extern "C" void kernel_launch(void* const* d_in, const int* in_sizes, int n_in,
                              void* d_out, int out_size, void* d_ws, size_t ws_size,
                              hipStream_t stream) {
  const float* x  = (const float*)d_in[0];
  const float* th = (const float*)d_in[1];
  const float* xi = (const float*)d_in[2];
  const float* sg = (const float*)d_in[3];
  const float* sl = (const float*)d_in[4];
  float* out = (float*)d_out;

  // ws layout: [sums 1KB][psiT 9][XhT 8][T2 64][T3 nI*8] images of 64K float2
  float* sums  = (float*)d_ws;
  float2* psiT = (float2*)((char*)d_ws + 1024);
  float2* XhT  = psiT + (size_t)9 * IMG;
  float2* T2   = XhT + (size_t)8 * IMG;   // U1h (transposed); early: temps below
  float2* T3   = T2 + (size_t)64 * IMG;   // U2 chunk temp
  float2* spat = T2;                      // 9 imgs (dead before U1 stage)
  float2* tmp9 = T2 + (size_t)9 * IMG;    // 9 imgs
  float2* xtmp = T2;                      // 8 imgs
  float2* s0t  = T2;                      // 8 imgs

  size_t t3off = 1024 + (size_t)(9 + 8 + 64) * IMG * sizeof(float2);
  int nI = 8;  // batches of i (bc) per U2 chunk; shrink if ws is small
  while (nI > 1 && t3off + (size_t)nI * 8 * IMG * sizeof(float2) > ws_size) nI >>= 1;

  dim3 B(256);
  k_sums<<<dim3(8), B, 0, stream>>>(th, xi, sg, sl, sums);
  k_spatial<<<dim3(256, 9), B, 0, stream>>>(th, xi, sg, sl, sums, spat);
  k_passT<<<dim3(64, 9), B, 0, stream>>>(spat, tmp9, -1.f);      // psi: fft n
  k_passS<<<dim3(64, 9), B, 0, stream>>>(tmp9, psiT, -1.f);      // psi: fft m -> psiT [n][m]
  k_passT_real<<<dim3(64, 8), B, 0, stream>>>(x, xtmp, -1.f);    // x: fft n
  k_passS<<<dim3(64, 8), B, 0, stream>>>(xtmp, XhT, -1.f);       // x: fft m -> XhT [n][m]
  k_s0_p1<<<dim3(64, 8), B, 0, stream>>>(XhT, psiT + (size_t)8 * IMG, s0t);
  k_s0_p2<<<dim3(64, 8), B, 0, stream>>>(s0t, out);
  k_u1_p1<<<dim3(64, 64), B, 0, stream>>>(XhT, psiT, out);
  k_u1_p2<<<dim3(64, 64), B, 0, stream>>>(out, T2);
  k_passS<<<dim3(64, 64), B, 0, stream>>>(T2, T2, -1.f);         // U1h: fft m in-place
  for (int f1 = 0; f1 < 8; ++f1)
    for (int i0 = 0; i0 < 8; i0 += nI) {
      k_u2_p1<<<dim3(64, nI * 8), B, 0, stream>>>(T2, psiT, T3, f1, i0);
      k_u2_p2<<<dim3(64, nI * 8), B, 0, stream>>>(T3, out, f1, i0);
    }
}

// Round 2
// 581.093 us; speedup vs baseline: 1.1088x; 1.1088x over previous
//
#include <hip/hip_runtime.h>
#include <math.h>

#define PI_F 3.14159265358979323846f
#define IMG 65536  // 256*256

__device__ __forceinline__ float2 cmul(float2 a, float2 b) {
  return make_float2(a.x * b.x - a.y * b.y, a.x * b.y + a.y * b.x);
}
__device__ __forceinline__ float2 shflx(float2 v, int m) {
  return make_float2(__shfl_xor(v.x, m, 64), __shfl_xor(v.y, m, 64));
}

// ---------------- register wave-FFT (256 = 64 lanes x 4 regs) ----------------
// Layout convention for ALL arrays (spatial and spectral): lane l holds
// positions l + 64*j (j = 0..3). Forward stores spectrum in a fixed
// permutation (bit-reversed k1); inverse consumes the same permutation, so
// pointwise products in the spectral domain are exact and no reorder is done.

// 64-pt DIF across lanes (natural lane index in, bit-reversed out), 4 regs.
__device__ __forceinline__ void fft64_dif(float2 v[4], int lane) {
  #pragma unroll
  for (int st = 5; st >= 0; --st) {
    int s = 1 << st;  // 32,16,8,4,2,1
    float ang = -PI_F * (float)(lane & (s - 1)) / (float)s;
    float sn, cs; __sincosf(ang, &sn, &cs);
    bool hi = (lane & s) != 0;
    #pragma unroll
    for (int r = 0; r < 4; ++r) {
      float2 p = shflx(v[r], s);
      if (hi) {
        float2 d = make_float2(p.x - v[r].x, p.y - v[r].y);
        v[r] = make_float2(d.x * cs - d.y * sn, d.x * sn + d.y * cs);
      } else {
        v[r] = make_float2(v[r].x + p.x, v[r].y + p.y);
      }
    }
  }
}

// 64-pt DIT across lanes (bit-reversed in, natural out), inverse sign.
__device__ __forceinline__ void fft64_dit(float2 v[4], int lane) {
  #pragma unroll
  for (int st = 0; st <= 5; ++st) {
    int s = 1 << st;  // 1,2,4,8,16,32
    float ang = PI_F * (float)(lane & (s - 1)) / (float)s;
    float sn, cs; __sincosf(ang, &sn, &cs);
    bool hi = (lane & s) != 0;
    #pragma unroll
    for (int r = 0; r < 4; ++r) {
      float2 p = shflx(v[r], s);
      if (hi) {
        float2 wb = make_float2(v[r].x * cs - v[r].y * sn, v[r].x * sn + v[r].y * cs);
        v[r] = make_float2(p.x - wb.x, p.y - wb.y);
      } else {
        float2 wb = make_float2(p.x * cs - p.y * sn, p.x * sn + p.y * cs);
        v[r] = make_float2(v[r].x + wb.x, v[r].y + wb.y);
      }
    }
  }
}

// forward 256-pt: input v[j] = x[lane + 64j]; output reg k2 holds
// X[k2 + 4*rev6(lane)] (stored back at lane + 64*k2 => fixed permutation).
__device__ __forceinline__ void fwd256(float2 v[4], int lane) {
  // radix-4 over j (W4 = -i)
  float2 e0 = make_float2(v[0].x + v[2].x, v[0].y + v[2].y);
  float2 o0 = make_float2(v[0].x - v[2].x, v[0].y - v[2].y);
  float2 e1 = make_float2(v[1].x + v[3].x, v[1].y + v[3].y);
  float2 o1 = make_float2(v[1].x - v[3].x, v[1].y - v[3].y);
  v[0] = make_float2(e0.x + e1.x, e0.y + e1.y);
  v[2] = make_float2(e0.x - e1.x, e0.y - e1.y);
  v[1] = make_float2(o0.x + o1.y, o0.y - o1.x);  // o0 - i*o1
  v[3] = make_float2(o0.x - o1.y, o0.y + o1.x);  // o0 + i*o1
  // twiddle W256^(lane*k2), forward sign
  float sn, cs; __sincosf(2.f * PI_F * (float)lane * (1.f / 256.f), &sn, &cs);
  float2 w1 = make_float2(cs, -sn);
  float2 w2 = cmul(w1, w1);
  float2 w3 = cmul(w2, w1);
  v[1] = cmul(v[1], w1); v[2] = cmul(v[2], w2); v[3] = cmul(v[3], w3);
  fft64_dif(v, lane);
}

// inverse 256-pt (unnormalized): input reg j loaded from pos lane + 64j of a
// forward-stored spectrum; output v[n2] = x[lane + 64*n2] (natural).
__device__ __forceinline__ void inv256(float2 v[4], int lane) {
  fft64_dit(v, lane);
  float sn, cs; __sincosf(2.f * PI_F * (float)lane * (1.f / 256.f), &sn, &cs);
  float2 w1 = make_float2(cs, sn);
  float2 w2 = cmul(w1, w1);
  float2 w3 = cmul(w2, w1);
  v[1] = cmul(v[1], w1); v[2] = cmul(v[2], w2); v[3] = cmul(v[3], w3);
  float2 e0 = make_float2(v[0].x + v[2].x, v[0].y + v[2].y);
  float2 o0 = make_float2(v[0].x - v[2].x, v[0].y - v[2].y);
  float2 e1 = make_float2(v[1].x + v[3].x, v[1].y + v[3].y);
  float2 o1 = make_float2(v[1].x - v[3].x, v[1].y - v[3].y);
  v[0] = make_float2(e0.x + e1.x, e0.y + e1.y);
  v[2] = make_float2(e0.x - e1.x, e0.y - e1.y);
  v[1] = make_float2(o0.x - o1.y, o0.y + o1.x);  // o0 + i*o1
  v[3] = make_float2(o0.x + o1.y, o0.y - o1.x);  // o0 - i*o1
}

// tile flush: tile[8][258] -> transposed global region OT (column t gets 8
// consecutive float2 at OT + t*256 + r0) as 4 x float4 (64B/thread, full lines)
__device__ __forceinline__ void tile_flush(float2 (*tile)[258], float2* OT, int r0) {
  __syncthreads();
  int t = threadIdx.x;
  float4* dst = (float4*)(OT + (size_t)t * 256 + r0);
  #pragma unroll
  for (int k = 0; k < 4; ++k) {
    float2 a = tile[2 * k][t], b = tile[2 * k + 1][t];
    dst[k] = make_float4(a.x, a.y, b.x, b.y);
  }
}

// ---------------- filter construction ----------------

__global__ __launch_bounds__(256) void k_sums(const float* th, const float* xi,
                                              const float* sg, const float* sl,
                                              float* sums) {
  int f = blockIdx.x, t = threadIdx.x;
  float c, s;
  sincosf(th[f], &s, &c);
  float X = xi[f], S = sg[f], SL = sl[f];
  float a0x = SL * c / S, a0y = SL * s / S, a1x = -s / S, a1y = c / S;
  float gs = 0.f, wr = 0.f, wi = 0.f;
  for (int p = t; p < IMG; p += 256) {
    float gm = (float)((p >> 8) - 128);
    float gn = (float)((p & 255) - 128);
    float r0 = a0x * gm + a0y * gn, r1 = a1x * gm + a1y * gn;
    float g = __expf(-0.5f * (r0 * r0 + r1 * r1));
    float sp, cp;
    sincosf(X * (c * gm + s * gn), &sp, &cp);
    gs += g; wr += cp * g; wi += sp * g;
  }
  __shared__ float red[3][256];
  red[0][t] = gs; red[1][t] = wr; red[2][t] = wi;
  __syncthreads();
  for (int o = 128; o > 0; o >>= 1) {
    if (t < o) {
      red[0][t] += red[0][t + o];
      red[1][t] += red[1][t + o];
      red[2][t] += red[2][t + o];
    }
    __syncthreads();
  }
  if (t == 0) {
    sums[f * 3 + 0] = red[0][0];
    sums[f * 3 + 1] = red[1][0];
    sums[f * 3 + 2] = red[2][0];
  }
}

__global__ __launch_bounds__(256) void k_spatial(const float* th, const float* xi,
                                                 const float* sg, const float* sl,
                                                 const float* sums, float2* spat) {
  int f = blockIdx.y;
  int p = blockIdx.x * 256 + threadIdx.x;
  int m = p >> 8, n = p & 255;
  float gm = (m < 128) ? (float)m : (float)(m - 256);
  float gn = (n < 128) ? (float)n : (float)(n - 256);
  bool isPhi = (f == 8);
  float T = isPhi ? 0.f : th[f];
  float X = isPhi ? 0.f : xi[f];
  float S = isPhi ? 3.2f : sg[f];
  float SL = isPhi ? 1.f : sl[f];
  float c, s;
  sincosf(T, &s, &c);
  float a0x = SL * c / S, a0y = SL * s / S, a1x = -s / S, a1y = c / S;
  float r0 = a0x * gm + a0y * gn, r1 = a1x * gm + a1y * gn;
  float g = __expf(-0.5f * (r0 * r0 + r1 * r1));
  float sp, cp;
  sincosf(X * (c * gm + s * gn), &sp, &cp);
  float re, im;
  if (!isPhi) {
    float gs = sums[f * 3];
    float Kr = sums[f * 3 + 1] / gs, Ki = sums[f * 3 + 2] / gs;
    re = (cp - Kr) * g;
    im = (sp - Ki) * g;
  } else {
    re = g;
    im = 0.f;
  }
  float inorm = SL / (2.f * PI_F * S * S);
  spat[(size_t)f * IMG + p] = make_float2(re * inorm, im * inorm);
}

// ---------------- FFT pass kernels ----------------
// tile kernels: grid (32, imgs), 8 rows/block (wave w does rows r0+w, r0+w+4)
// straight kernels: grid (64, imgs), 1 row/wave

__global__ __launch_bounds__(256) void k_fwdT(const float2* __restrict__ in,
                                              float2* __restrict__ out) {
  __shared__ float2 tile[8][258];
  int w = threadIdx.x >> 6, l = threadIdx.x & 63;
  int img = blockIdx.y, r0 = blockIdx.x * 8;
  const float2* ib = in + (size_t)img * IMG;
  #pragma unroll
  for (int it = 0; it < 2; ++it) {
    int ri = w + 4 * it;
    const float2* ip = ib + (size_t)(r0 + ri) * 256;
    float2 v[4];
    #pragma unroll
    for (int j = 0; j < 4; ++j) v[j] = ip[l + 64 * j];
    fwd256(v, l);
    #pragma unroll
    for (int j = 0; j < 4; ++j) tile[ri][l + 64 * j] = v[j];
  }
  tile_flush(tile, out + (size_t)img * IMG, r0);
}

__global__ __launch_bounds__(256) void k_fwdT_real(const float* __restrict__ in,
                                                   float2* __restrict__ out) {
  __shared__ float2 tile[8][258];
  int w = threadIdx.x >> 6, l = threadIdx.x & 63;
  int img = blockIdx.y, r0 = blockIdx.x * 8;
  const float* ib = in + (size_t)img * IMG;
  #pragma unroll
  for (int it = 0; it < 2; ++it) {
    int ri = w + 4 * it;
    const float* ip = ib + (size_t)(r0 + ri) * 256;
    float2 v[4];
    #pragma unroll
    for (int j = 0; j < 4; ++j) v[j] = make_float2(ip[l + 64 * j], 0.f);
    fwd256(v, l);
    #pragma unroll
    for (int j = 0; j < 4; ++j) tile[ri][l + 64 * j] = v[j];
  }
  tile_flush(tile, out + (size_t)img * IMG, r0);
}

__global__ __launch_bounds__(256) void k_fwdS(const float2* in, float2* out) {
  int w = threadIdx.x >> 6, l = threadIdx.x & 63;
  int img = blockIdx.y, row = blockIdx.x * 4 + w;
  const float2* ip = in + (size_t)img * IMG + (size_t)row * 256;
  float2 v[4];
  #pragma unroll
  for (int j = 0; j < 4; ++j) v[j] = ip[l + 64 * j];
  fwd256(v, l);
  float2* op = out + (size_t)img * IMG + (size_t)row * 256;
  #pragma unroll
  for (int j = 0; j < 4; ++j) op[l + 64 * j] = v[j];
}

// multiply + inverse + transposed store (tile)
__device__ __forceinline__ void mul_inv_tile(const float2* A, const float2* P,
                                             float2* OT, int r0, int w, int l,
                                             float2 (*tile)[258]) {
  #pragma unroll
  for (int it = 0; it < 2; ++it) {
    int ri = w + 4 * it;
    const float2* ap = A + (size_t)(r0 + ri) * 256;
    const float2* pp = P + (size_t)(r0 + ri) * 256;
    float2 v[4];
    #pragma unroll
    for (int j = 0; j < 4; ++j) v[j] = cmul(ap[l + 64 * j], pp[l + 64 * j]);
    inv256(v, l);
    #pragma unroll
    for (int j = 0; j < 4; ++j) tile[ri][l + 64 * j] = v[j];
  }
  tile_flush(tile, OT, r0);
}

__global__ __launch_bounds__(256) void k_s0_p1(const float2* __restrict__ XhT,
                                               const float2* __restrict__ phiT,
                                               float2* __restrict__ s0t) {
  __shared__ float2 tile[8][258];
  int w = threadIdx.x >> 6, l = threadIdx.x & 63;
  int img = blockIdx.y, r0 = blockIdx.x * 8;
  mul_inv_tile(XhT + (size_t)img * IMG, phiT, s0t + (size_t)img * IMG, r0, w, l, tile);
}

__global__ __launch_bounds__(256) void k_s0_p2(const float2* __restrict__ s0t,
                                               float* __restrict__ out) {
  int w = threadIdx.x >> 6, l = threadIdx.x & 63;
  int img = blockIdx.y, row = blockIdx.x * 4 + w;
  const float2* ip = s0t + (size_t)img * IMG + (size_t)row * 256;
  float2 v[4];
  #pragma unroll
  for (int j = 0; j < 4; ++j) v[j] = ip[l + 64 * j];
  inv256(v, l);
  float* op = out + ((size_t)img * 73) * IMG + (size_t)row * 256;
  #pragma unroll
  for (int j = 0; j < 4; ++j) op[l + 64 * j] = v[j].x * (1.f / 65536.f);
}

__global__ __launch_bounds__(256) void k_u1_p1(const float2* __restrict__ XhT,
                                               const float2* __restrict__ psiT,
                                               float* out) {
  __shared__ float2 tile[8][258];
  int w = threadIdx.x >> 6, l = threadIdx.x & 63;
  int u = blockIdx.y, i = u >> 3, f = u & 7;
  int r0 = blockIdx.x * 8;
  float2* t1 = (float2*)out + ((size_t)(i * 73 + 9 + 2 * f)) * 32768;
  mul_inv_tile(XhT + (size_t)i * IMG, psiT + (size_t)f * IMG, t1, r0, w, l, tile);
}

// inverse along n -> modulus -> U1 out (straight) ; forward along n -> T2 (transposed)
__global__ __launch_bounds__(256) void k_u1_p2(float* out, float2* T2) {
  __shared__ float2 tile[8][258];
  int w = threadIdx.x >> 6, l = threadIdx.x & 63;
  int u = blockIdx.y, i = u >> 3, f = u & 7;
  int r0 = blockIdx.x * 8;
  const float2* t1 = (const float2*)out + ((size_t)(i * 73 + 9 + 2 * f)) * 32768;
  float* uo = out + ((size_t)(i * 73 + 1 + f)) * IMG;
  #pragma unroll
  for (int it = 0; it < 2; ++it) {
    int ri = w + 4 * it, row = r0 + ri;
    const float2* ip = t1 + (size_t)row * 256;
    float2 v[4];
    #pragma unroll
    for (int j = 0; j < 4; ++j) v[j] = ip[l + 64 * j];
    inv256(v, l);
    float* up = uo + (size_t)row * 256;
    #pragma unroll
    for (int j = 0; j < 4; ++j) {
      float2 z = v[j];
      float mod = sqrtf(z.x * z.x + z.y * z.y) * (1.f / 65536.f);
      up[l + 64 * j] = mod;
      v[j] = make_float2(mod, 0.f);
    }
    fwd256(v, l);
    #pragma unroll
    for (int j = 0; j < 4; ++j) tile[ri][l + 64 * j] = v[j];
  }
  tile_flush(tile, T2 + (size_t)u * IMG, r0);
}

__global__ __launch_bounds__(256) void k_u2_p1(const float2* __restrict__ U1hT,
                                               const float2* __restrict__ psiT,
                                               float2* __restrict__ T3,
                                               int f1, int i0) {
  __shared__ float2 tile[8][258];
  int w = threadIdx.x >> 6, l = threadIdx.x & 63;
  int y = blockIdx.y, ii = i0 + (y >> 3), f2 = y & 7;
  int r0 = blockIdx.x * 8;
  mul_inv_tile(U1hT + ((size_t)(ii * 8 + f1)) * IMG, psiT + (size_t)f2 * IMG,
               T3 + (size_t)y * IMG, r0, w, l, tile);
}

__global__ __launch_bounds__(256) void k_u2_p2(const float2* __restrict__ T3,
                                               float* __restrict__ out,
                                               int f1, int i0) {
  int w = threadIdx.x >> 6, l = threadIdx.x & 63;
  int y = blockIdx.y, ii = i0 + (y >> 3), f2 = y & 7;
  int row = blockIdx.x * 4 + w;
  const float2* ip = T3 + (size_t)y * IMG + (size_t)row * 256;
  float2 v[4];
  #pragma unroll
  for (int j = 0; j < 4; ++j) v[j] = ip[l + 64 * j];
  inv256(v, l);
  float* op = out + ((size_t)(ii * 73 + 9 + f1 * 8 + f2)) * IMG + (size_t)row * 256;
  #pragma unroll
  for (int j = 0; j < 4; ++j) {
    float2 z = v[j];
    op[l + 64 * j] = sqrtf(z.x * z.x + z.y * z.y) * (1.f / 65536.f);
  }
}

extern "C" void kernel_launch(void* const* d_in, const int* in_sizes, int n_in,
                              void* d_out, int out_size, void* d_ws, size_t ws_size,
                              hipStream_t stream) {
  const float* x  = (const float*)d_in[0];
  const float* th = (const float*)d_in[1];
  const float* xi = (const float*)d_in[2];
  const float* sg = (const float*)d_in[3];
  const float* sl = (const float*)d_in[4];
  float* out = (float*)d_out;

  float* sums  = (float*)d_ws;
  float2* psiT = (float2*)((char*)d_ws + 1024);
  float2* XhT  = psiT + (size_t)9 * IMG;
  float2* T2   = XhT + (size_t)8 * IMG;   // U1h (64 imgs); early: temps below
  float2* T3   = T2 + (size_t)64 * IMG;   // U2 chunk temp
  float2* spat = T2;                      // 9 imgs (dead before U1 stage)
  float2* tmp9 = T2 + (size_t)9 * IMG;    // 9 imgs
  float2* xtmp = T2;                      // 8 imgs
  float2* s0t  = T2;                      // 8 imgs

  size_t t3off = 1024 + (size_t)(9 + 8 + 64) * IMG * sizeof(float2);
  int nI = 8;
  while (nI > 1 && t3off + (size_t)nI * 8 * IMG * sizeof(float2) > ws_size) nI >>= 1;

  dim3 B(256);
  k_sums<<<dim3(8), B, 0, stream>>>(th, xi, sg, sl, sums);
  k_spatial<<<dim3(256, 9), B, 0, stream>>>(th, xi, sg, sl, sums, spat);
  k_fwdT<<<dim3(32, 9), B, 0, stream>>>(spat, tmp9);         // psi: fft n -> [kn][m]
  k_fwdS<<<dim3(64, 9), B, 0, stream>>>(tmp9, psiT);         // psi: fft m -> psiT
  k_fwdT_real<<<dim3(32, 8), B, 0, stream>>>(x, xtmp);       // x: fft n
  k_fwdS<<<dim3(64, 8), B, 0, stream>>>(xtmp, XhT);          // x: fft m -> XhT
  k_s0_p1<<<dim3(32, 8), B, 0, stream>>>(XhT, psiT + (size_t)8 * IMG, s0t);
  k_s0_p2<<<dim3(64, 8), B, 0, stream>>>(s0t, out);
  k_u1_p1<<<dim3(32, 64), B, 0, stream>>>(XhT, psiT, out);
  k_u1_p2<<<dim3(32, 64), B, 0, stream>>>(out, T2);
  k_fwdS<<<dim3(64, 64), B, 0, stream>>>(T2, T2);            // U1h: fft m in-place
  for (int f1 = 0; f1 < 8; ++f1)
    for (int i0 = 0; i0 < 8; i0 += nI) {
      k_u2_p1<<<dim3(32, nI * 8), B, 0, stream>>>(T2, psiT, T3, f1, i0);
      k_u2_p2<<<dim3(64, nI * 8), B, 0, stream>>>(T3, out, f1, i0);
    }
}

// Round 3
// 539.495 us; speedup vs baseline: 1.1943x; 1.0771x over previous
//
#include <hip/hip_runtime.h>
#include <math.h>

#define PI_F 3.14159265358979323846f
#define IMG 65536  // 256*256

__device__ __forceinline__ float2 cmul(float2 a, float2 b) {
  return make_float2(a.x * b.x - a.y * b.y, a.x * b.y + a.y * b.x);
}
__device__ __forceinline__ float2 shflx(float2 v, int m) {
  return make_float2(__shfl_xor(v.x, m, 64), __shfl_xor(v.y, m, 64));
}

// Precomputed per-lane twiddles. w[t] is the stage twiddle for s = 32>>t
// (identity on lo lanes). q1..q3 are the radix-4 column twiddles.
struct Tw { float2 w[5]; float2 q1, q2, q3; };

// sign = -1 forward, +1 inverse
__device__ __forceinline__ void tw_make(int lane, float sign, Tw& T) {
  #pragma unroll
  for (int t = 0; t < 5; ++t) {
    int s = 32 >> t;
    if (lane & s) {
      float ang = sign * PI_F * (float)(lane & (s - 1)) / (float)s;
      float sn, cs; __sincosf(ang, &sn, &cs);
      T.w[t] = make_float2(cs, sn);
    } else {
      T.w[t] = make_float2(1.f, 0.f);
    }
  }
  float ang = sign * 2.f * PI_F * (float)lane * (1.f / 256.f);
  float sn, cs; __sincosf(ang, &sn, &cs);
  T.q1 = make_float2(cs, sn);
  T.q2 = cmul(T.q1, T.q1);
  T.q3 = cmul(T.q2, T.q1);
}

// ---- batched 256-pt FFT: 8 rows per wave, 4 regs/row, 64 lanes ----
// Layout: lane l, reg j <-> position/slot l + 64*j. Forward emits a fixed
// permuted slot order; inverse consumes the same order (products are
// slot-wise, so the permutation never needs materializing).

__device__ __forceinline__ void fwd256_b(float2 (&v)[8][4], int lane, const Tw& T) {
  #pragma unroll
  for (int r = 0; r < 8; ++r) {
    float2 a = v[r][0], b = v[r][1], c = v[r][2], d = v[r][3];
    float2 e0 = make_float2(a.x + c.x, a.y + c.y);
    float2 o0 = make_float2(a.x - c.x, a.y - c.y);
    float2 e1 = make_float2(b.x + d.x, b.y + d.y);
    float2 o1 = make_float2(b.x - d.x, b.y - d.y);
    v[r][0] = make_float2(e0.x + e1.x, e0.y + e1.y);
    v[r][2] = cmul(make_float2(e0.x - e1.x, e0.y - e1.y), T.q2);
    v[r][1] = cmul(make_float2(o0.x + o1.y, o0.y - o1.x), T.q1);  // o0 - i*o1
    v[r][3] = cmul(make_float2(o0.x - o1.y, o0.y + o1.x), T.q3);  // o0 + i*o1
  }
  #pragma unroll
  for (int t = 0; t < 5; ++t) {
    int s = 32 >> t;
    float sg = (lane & s) ? -1.f : 1.f;
    float2 w = T.w[t];
    #pragma unroll
    for (int r = 0; r < 8; ++r)
      #pragma unroll
      for (int j = 0; j < 4; ++j) {
        float2 p = shflx(v[r][j], s);
        float2 u = make_float2(p.x + sg * v[r][j].x, p.y + sg * v[r][j].y);
        v[r][j] = cmul(u, w);
      }
  }
  { // s = 1, twiddle = 1
    float sg = (lane & 1) ? -1.f : 1.f;
    #pragma unroll
    for (int r = 0; r < 8; ++r)
      #pragma unroll
      for (int j = 0; j < 4; ++j) {
        float2 p = shflx(v[r][j], 1);
        v[r][j] = make_float2(p.x + sg * v[r][j].x, p.y + sg * v[r][j].y);
      }
  }
}

__device__ __forceinline__ void inv256_b(float2 (&v)[8][4], int lane, const Tw& T) {
  { // s = 1 first, twiddle = 1
    float sg = (lane & 1) ? -1.f : 1.f;
    #pragma unroll
    for (int r = 0; r < 8; ++r)
      #pragma unroll
      for (int j = 0; j < 4; ++j) {
        float2 p = shflx(v[r][j], 1);
        v[r][j] = make_float2(p.x + sg * v[r][j].x, p.y + sg * v[r][j].y);
      }
  }
  #pragma unroll
  for (int t = 0; t < 5; ++t) {
    int s = 2 << t;                 // 2,4,8,16,32
    float sg = (lane & s) ? -1.f : 1.f;
    float2 w = T.w[4 - t];          // w[] indexed by s = 32>>idx
    #pragma unroll
    for (int r = 0; r < 8; ++r)
      #pragma unroll
      for (int j = 0; j < 4; ++j) {
        float2 z = cmul(v[r][j], w);
        float2 p = shflx(z, s);
        v[r][j] = make_float2(p.x + sg * z.x, p.y + sg * z.y);
      }
  }
  #pragma unroll
  for (int r = 0; r < 8; ++r) {
    float2 a = v[r][0], b = cmul(v[r][1], T.q1);
    float2 c = cmul(v[r][2], T.q2), d = cmul(v[r][3], T.q3);
    float2 e0 = make_float2(a.x + c.x, a.y + c.y);
    float2 o0 = make_float2(a.x - c.x, a.y - c.y);
    float2 e1 = make_float2(b.x + d.x, b.y + d.y);
    float2 o1 = make_float2(b.x - d.x, b.y - d.y);
    v[r][0] = make_float2(e0.x + e1.x, e0.y + e1.y);
    v[r][2] = make_float2(e0.x - e1.x, e0.y - e1.y);
    v[r][1] = make_float2(o0.x - o1.y, o0.y + o1.x);  // o0 + i*o1
    v[r][3] = make_float2(o0.x + o1.y, o0.y - o1.x);  // o0 - i*o1
  }
}

// ---- memory helpers (no LDS anywhere) ----

__device__ __forceinline__ void loadRows(const float2* bp, int r0, float2 (&v)[8][4], int l) {
  #pragma unroll
  for (int ri = 0; ri < 8; ++ri) {
    const float2* rp = bp + (size_t)(r0 + ri) * 256 + l;
    #pragma unroll
    for (int j = 0; j < 4; ++j) v[ri][j] = rp[64 * j];
  }
}
__device__ __forceinline__ void storeRows(float2* bp, int r0, float2 (&v)[8][4], int l) {
  #pragma unroll
  for (int ri = 0; ri < 8; ++ri) {
    float2* rp = bp + (size_t)(r0 + ri) * 256 + l;
    #pragma unroll
    for (int j = 0; j < 4; ++j) rp[64 * j] = v[ri][j];
  }
}
// transposed store: column c = l+64j gets rows r0..r0+7 contiguous (64 B/lane/j)
__device__ __forceinline__ void storeT(float2* OT, int r0, float2 (&v)[8][4], int l) {
  #pragma unroll
  for (int j = 0; j < 4; ++j) {
    int c = l + 64 * j;
    float4* dst = (float4*)(OT + (size_t)c * 256 + r0);
    #pragma unroll
    for (int k = 0; k < 4; ++k)
      dst[k] = make_float4(v[2 * k][j].x, v[2 * k][j].y,
                           v[2 * k + 1][j].x, v[2 * k + 1][j].y);
  }
}

// ---------------- filter construction ----------------

__global__ __launch_bounds__(256) void k_sums(const float* th, const float* xi,
                                              const float* sg, const float* sl,
                                              float* sums) {
  int f = blockIdx.x, t = threadIdx.x;
  float c, s;
  sincosf(th[f], &s, &c);
  float X = xi[f], S = sg[f], SL = sl[f];
  float a0x = SL * c / S, a0y = SL * s / S, a1x = -s / S, a1y = c / S;
  float gs = 0.f, wr = 0.f, wi = 0.f;
  for (int p = t; p < IMG; p += 256) {
    float gm = (float)((p >> 8) - 128);
    float gn = (float)((p & 255) - 128);
    float r0 = a0x * gm + a0y * gn, r1 = a1x * gm + a1y * gn;
    float g = __expf(-0.5f * (r0 * r0 + r1 * r1));
    float sp, cp;
    sincosf(X * (c * gm + s * gn), &sp, &cp);
    gs += g; wr += cp * g; wi += sp * g;
  }
  __shared__ float red[3][256];
  red[0][t] = gs; red[1][t] = wr; red[2][t] = wi;
  __syncthreads();
  for (int o = 128; o > 0; o >>= 1) {
    if (t < o) {
      red[0][t] += red[0][t + o];
      red[1][t] += red[1][t + o];
      red[2][t] += red[2][t + o];
    }
    __syncthreads();
  }
  if (t == 0) {
    sums[f * 3 + 0] = red[0][0];
    sums[f * 3 + 1] = red[1][0];
    sums[f * 3 + 2] = red[2][0];
  }
}

// spatial eval (ifftshift folded) + forward FFT along n + transposed store.
// grid (8, 9); f = 8 is phi.
__global__ __launch_bounds__(256) void k_psi_p1(const float* th, const float* xi,
                                                const float* sg_, const float* sl,
                                                const float* sums, float2* outT) {
  int w = threadIdx.x >> 6, l = threadIdx.x & 63;
  int f = blockIdx.y;
  int r0 = blockIdx.x * 32 + w * 8;
  bool isPhi = (f == 8);
  float T_ = 0.f, X = 0.f, S = 3.2f, SL = 1.f, Kr = 0.f, Ki = 0.f;
  if (!isPhi) {
    T_ = th[f]; X = xi[f]; S = sg_[f]; SL = sl[f];
    float gs = sums[f * 3];
    Kr = sums[f * 3 + 1] / gs;
    Ki = sums[f * 3 + 2] / gs;
  }
  float c, s;
  sincosf(T_, &s, &c);
  float a0x = SL * c / S, a0y = SL * s / S, a1x = -s / S, a1y = c / S;
  float inorm = SL / (2.f * PI_F * S * S);
  float2 v[8][4];
  #pragma unroll
  for (int ri = 0; ri < 8; ++ri) {
    int m = r0 + ri;
    float gm = (m < 128) ? (float)m : (float)(m - 256);
    #pragma unroll
    for (int j = 0; j < 4; ++j) {
      int n = l + 64 * j;
      float gn = (n < 128) ? (float)n : (float)(n - 256);
      float rr0 = a0x * gm + a0y * gn, rr1 = a1x * gm + a1y * gn;
      float g = __expf(-0.5f * (rr0 * rr0 + rr1 * rr1));
      float sp, cp;
      sincosf(X * (c * gm + s * gn), &sp, &cp);
      float re = isPhi ? g : (cp - Kr) * g;
      float im = isPhi ? 0.f : (sp - Ki) * g;
      v[ri][j] = make_float2(re * inorm, im * inorm);
    }
  }
  Tw T; tw_make(l, -1.f, T);
  fwd256_b(v, l, T);
  storeT(outT + (size_t)f * IMG, r0, v, l);
}

// real input, forward FFT along n, transposed store. grid (8, 8)
__global__ __launch_bounds__(256) void k_x_p1(const float* __restrict__ x,
                                              float2* __restrict__ outT) {
  int w = threadIdx.x >> 6, l = threadIdx.x & 63;
  int img = blockIdx.y, r0 = blockIdx.x * 32 + w * 8;
  float2 v[8][4];
  #pragma unroll
  for (int ri = 0; ri < 8; ++ri) {
    const float* rp = x + (size_t)img * IMG + (size_t)(r0 + ri) * 256 + l;
    #pragma unroll
    for (int j = 0; j < 4; ++j) v[ri][j] = make_float2(rp[64 * j], 0.f);
  }
  Tw T; tw_make(l, -1.f, T);
  fwd256_b(v, l, T);
  storeT(outT + (size_t)img * IMG, r0, v, l);
}

// straight forward FFT (in==out OK). grid (8, imgs)
__global__ __launch_bounds__(256) void k_fwdS(const float2* in, float2* out) {
  int w = threadIdx.x >> 6, l = threadIdx.x & 63;
  int img = blockIdx.y, r0 = blockIdx.x * 32 + w * 8;
  float2 v[8][4];
  loadRows(in + (size_t)img * IMG, r0, v, l);
  Tw T; tw_make(l, -1.f, T);
  fwd256_b(v, l, T);
  storeRows(out + (size_t)img * IMG, r0, v, l);
}

// U1 pass1 (incl. phi as f=8): Xh*psi -> inv over m -> transposed -> T1 (parked
// in out's U2 slots). grid (8, 72); y = i*9 + f
__global__ __launch_bounds__(256) void k_u1_p1(const float2* __restrict__ XhT,
                                               const float2* __restrict__ psiT,
                                               float* out) {
  int w = threadIdx.x >> 6, l = threadIdx.x & 63;
  int y = blockIdx.y, i = y / 9, f = y - i * 9;
  int r0 = blockIdx.x * 32 + w * 8;
  const float2* A = XhT + (size_t)i * IMG;
  const float2* P = psiT + (size_t)f * IMG;
  float2 v[8][4];
  #pragma unroll
  for (int ri = 0; ri < 8; ++ri) {
    const float2* ap = A + (size_t)(r0 + ri) * 256 + l;
    const float2* pp = P + (size_t)(r0 + ri) * 256 + l;
    #pragma unroll
    for (int j = 0; j < 4; ++j) v[ri][j] = cmul(ap[64 * j], pp[64 * j]);
  }
  Tw T; tw_make(l, 1.f, T);
  inv256_b(v, l, T);
  storeT((float2*)out + ((size_t)(i * 73 + 9 + 2 * f)) * 32768, r0, v, l);
}

// U1 pass2: T1 -> inv over n. f<8: modulus -> U1 out, fwd over n -> T2 (transposed).
// f==8: real part -> S0 out. grid (8, 72)
__global__ __launch_bounds__(256) void k_u1_p2(float* out, float2* T2) {
  int w = threadIdx.x >> 6, l = threadIdx.x & 63;
  int y = blockIdx.y, i = y / 9, f = y - i * 9;
  int r0 = blockIdx.x * 32 + w * 8;
  float2 v[8][4];
  loadRows((const float2*)out + ((size_t)(i * 73 + 9 + 2 * f)) * 32768, r0, v, l);
  Tw Ti; tw_make(l, 1.f, Ti);
  inv256_b(v, l, Ti);
  if (f == 8) {
    float* op = out + (size_t)(i * 73) * IMG;
    #pragma unroll
    for (int ri = 0; ri < 8; ++ri)
      #pragma unroll
      for (int j = 0; j < 4; ++j)
        op[(size_t)(r0 + ri) * 256 + l + 64 * j] = v[ri][j].x * (1.f / 65536.f);
    return;
  }
  float* uo = out + (size_t)(i * 73 + 1 + f) * IMG;
  #pragma unroll
  for (int ri = 0; ri < 8; ++ri)
    #pragma unroll
    for (int j = 0; j < 4; ++j) {
      float2 z = v[ri][j];
      float mod = sqrtf(z.x * z.x + z.y * z.y) * (1.f / 65536.f);
      uo[(size_t)(r0 + ri) * 256 + l + 64 * j] = mod;
      v[ri][j] = make_float2(mod, 0.f);
    }
  Tw Tf; tw_make(l, -1.f, Tf);
  fwd256_b(v, l, Tf);
  storeT(T2 + (size_t)(i * 8 + f) * IMG, r0, v, l);
}

// U2 pass1: U1hT[ii*8+f1]*psiT[f2] -> inv over m -> transposed -> T3.
// grid (8, CQ*8); y -> q = q0 + y/8 (q = f1*8+ii), f2 = y&7
__global__ __launch_bounds__(256) void k_u2_p1(const float2* __restrict__ U1hT,
                                               const float2* __restrict__ psiT,
                                               float2* __restrict__ T3, int q0) {
  int w = threadIdx.x >> 6, l = threadIdx.x & 63;
  int y = blockIdx.y, q = q0 + (y >> 3), f2 = y & 7;
  int f1 = q >> 3, ii = q & 7;
  int r0 = blockIdx.x * 32 + w * 8;
  const float2* A = U1hT + (size_t)(ii * 8 + f1) * IMG;
  const float2* P = psiT + (size_t)f2 * IMG;
  float2 v[8][4];
  #pragma unroll
  for (int ri = 0; ri < 8; ++ri) {
    const float2* ap = A + (size_t)(r0 + ri) * 256 + l;
    const float2* pp = P + (size_t)(r0 + ri) * 256 + l;
    #pragma unroll
    for (int j = 0; j < 4; ++j) v[ri][j] = cmul(ap[64 * j], pp[64 * j]);
  }
  Tw T; tw_make(l, 1.f, T);
  inv256_b(v, l, T);
  storeT(T3 + (size_t)y * IMG, r0, v, l);
}

// U2 pass2: T3 -> inv over n -> modulus -> out. grid (8, CQ*8)
__global__ __launch_bounds__(256) void k_u2_p2(const float2* __restrict__ T3,
                                               float* __restrict__ out, int q0) {
  int w = threadIdx.x >> 6, l = threadIdx.x & 63;
  int y = blockIdx.y, q = q0 + (y >> 3), f2 = y & 7;
  int f1 = q >> 3, ii = q & 7;
  int r0 = blockIdx.x * 32 + w * 8;
  float2 v[8][4];
  loadRows(T3 + (size_t)y * IMG, r0, v, l);
  Tw T; tw_make(l, 1.f, T);
  inv256_b(v, l, T);
  float* op = out + (size_t)(ii * 73 + 9 + f1 * 8 + f2) * IMG;
  #pragma unroll
  for (int ri = 0; ri < 8; ++ri)
    #pragma unroll
    for (int j = 0; j < 4; ++j) {
      float2 z = v[ri][j];
      op[(size_t)(r0 + ri) * 256 + l + 64 * j] =
          sqrtf(z.x * z.x + z.y * z.y) * (1.f / 65536.f);
    }
}

extern "C" void kernel_launch(void* const* d_in, const int* in_sizes, int n_in,
                              void* d_out, int out_size, void* d_ws, size_t ws_size,
                              hipStream_t stream) {
  const float* x  = (const float*)d_in[0];
  const float* th = (const float*)d_in[1];
  const float* xi = (const float*)d_in[2];
  const float* sg = (const float*)d_in[3];
  const float* sl = (const float*)d_in[4];
  float* out = (float*)d_out;

  // ws: [sums 1KB][psiT 9][XhT 8][T2 64][T3 CQ*8] images of 64K float2
  float* sums  = (float*)d_ws;
  float2* psiT = (float2*)((char*)d_ws + 1024);
  float2* XhT  = psiT + (size_t)9 * IMG;
  float2* T2   = XhT + (size_t)8 * IMG;   // U1h (64 imgs); early temp region
  float2* T3   = T2 + (size_t)64 * IMG;
  float2* tmp9 = T2;                      // psi pass1 temp (9 imgs, dead early)
  float2* xtmp = T2;                      // x pass1 temp (8 imgs, dead early)

  size_t base = 1024 + (size_t)(9 + 8 + 64) * IMG * sizeof(float2);
  int CQ = 64;  // (f1,ii) combos per U2 chunk; each combo = 8 images of T3
  while (CQ > 1 && base + (size_t)CQ * 8 * IMG * sizeof(float2) > ws_size) CQ >>= 1;

  dim3 B(256);
  k_sums  <<<dim3(8),     B, 0, stream>>>(th, xi, sg, sl, sums);
  k_psi_p1<<<dim3(8, 9),  B, 0, stream>>>(th, xi, sg, sl, sums, tmp9);
  k_fwdS  <<<dim3(8, 9),  B, 0, stream>>>(tmp9, psiT);     // psi: fft m -> psiT
  k_x_p1  <<<dim3(8, 8),  B, 0, stream>>>(x, xtmp);        // x: fft n
  k_fwdS  <<<dim3(8, 8),  B, 0, stream>>>(xtmp, XhT);      // x: fft m -> XhT
  k_u1_p1 <<<dim3(8, 72), B, 0, stream>>>(XhT, psiT, out); // S0+U1 pass1 -> T1
  k_u1_p2 <<<dim3(8, 72), B, 0, stream>>>(out, T2);        // S0/U1 out, fwd -> T2
  k_fwdS  <<<dim3(8, 64), B, 0, stream>>>(T2, T2);         // U1h: fft m in-place
  for (int q0 = 0; q0 < 64; q0 += CQ) {
    k_u2_p1<<<dim3(8, CQ * 8), B, 0, stream>>>(T2, psiT, T3, q0);
    k_u2_p2<<<dim3(8, CQ * 8), B, 0, stream>>>(T3, out, q0);
  }
}